// Round 3
// baseline (305.569 us; speedup 1.0000x reference)
//
#include <hip/hip_runtime.h>
#include <cmath>

// K[n,m] = sv^2 * sum_p (x1[n,p]-off)*(x2[m,p]-off) + sb^2,  N=M=8192, P=16.
// Output 256 MiB fp32 -> write-BW-bound. Fill kernel on the same box proves
// 6.5 TB/s (163 us / GiB); floor for 256 MiB is ~41 us.
//
// R3 = R2 (LDS-free, barrier-free) + the two store-path fixes R2 lacked:
//  - __builtin_nontemporal_store for the output: 256 MiB of streaming writes
//    should not churn the 32 MiB L2 (write-back pressure was the last
//    mechanism distinguishing us from the 6.5 TB/s fill).
//  - Explicit 1-row software pipeline (named-register rotation, fully
//    unrolled): next row's 64 B x1 load is issued before the current row's
//    64 fmac + store, so the uniform-load latency never gates store issue.
//
// Structure: lane owns 4 output columns; C[c][p]=sv^2*(x2[c0+c][p]-off) in
// 64 VGPR loaded once; bias[c]=sb^2-off*sum_p C[c][p] folds the offset term:
// out = sum_p x1[n][p]*C[c][p] + bias[c]  (exact algebra). Per row per lane:
// 64 fmac + one 16 B nt store (wave instr = 1 KiB contiguous).
// Block: 256 threads / 4 waves; tile 32 rows x 1024 cols; grid 8 x 256.

typedef float f32x4 __attribute__((ext_vector_type(4)));

#define ROWS_PER_BLOCK 32
#define BLOCK_COLS 1024   // 4 waves * 64 lanes * 4 cols

__global__ __launch_bounds__(256, 4) void linear_kernel(
    const float* __restrict__ x1, const float* __restrict__ x2,
    const float* __restrict__ p_lsb, const float* __restrict__ p_lsv,
    const float* __restrict__ p_off, float* __restrict__ out,
    int n, int m)
{
    const int lane = threadIdx.x & 63;
    const int wid  = threadIdx.x >> 6;
    const int c0   = blockIdx.x * BLOCK_COLS + wid * 256 + (lane << 2);
    const int n0   = blockIdx.y * ROWS_PER_BLOCK;

    const float off = p_off[0];
    const float sv  = expf(p_lsv[0]);
    const float sb  = expf(p_lsb[0]);
    const float sv2 = sv * sv;
    const float sb2 = sb * sb;

    // ---- One-time: x2 fragment -> registers (all indices compile-time) ----
    float C[4][16];
    f32x4 bias;
    #pragma unroll
    for (int c = 0; c < 4; ++c) {
        const f32x4* g = (const f32x4*)(x2 + (size_t)(c0 + c) * 16);
        float s = 0.0f;
        #pragma unroll
        for (int q = 0; q < 4; ++q) {
            f32x4 v = g[q];
            #pragma unroll
            for (int j = 0; j < 4; ++j) {
                const float t = sv2 * (v[j] - off);
                C[c][q * 4 + j] = t;
                s += t;
            }
        }
        bias[c] = sb2 - off * s;
    }

    float* orow = out + (size_t)n0 * m + c0;
    const f32x4* arow = (const f32x4*)(x1 + (size_t)n0 * 16);

#define FMA4(Av, base)                                                  \
    _Pragma("unroll")                                                   \
    for (int j = 0; j < 4; ++j) {                                       \
        acc[0] = fmaf(Av[j], C[0][(base) + j], acc[0]);                 \
        acc[1] = fmaf(Av[j], C[1][(base) + j], acc[1]);                 \
        acc[2] = fmaf(Av[j], C[2][(base) + j], acc[2]);                 \
        acc[3] = fmaf(Av[j], C[3][(base) + j], acc[3]);                 \
    }

#define COMPUTE_STORE(A0, A1, A2, A3) do {                              \
        f32x4 acc = bias;                                               \
        FMA4(A0, 0) FMA4(A1, 4) FMA4(A2, 8) FMA4(A3, 12)               \
        __builtin_nontemporal_store(acc, (f32x4*)orow);                 \
        orow += m;                                                      \
    } while (0)

    // ---- Software-pipelined row loop: load row r+1, then compute/store r ----
    f32x4 a0 = arow[0], a1 = arow[1], a2 = arow[2], a3 = arow[3];
    #pragma unroll
    for (int r = 0; r < ROWS_PER_BLOCK - 1; ++r) {
        const f32x4 b0 = arow[(r + 1) * 4 + 0];
        const f32x4 b1 = arow[(r + 1) * 4 + 1];
        const f32x4 b2 = arow[(r + 1) * 4 + 2];
        const f32x4 b3 = arow[(r + 1) * 4 + 3];
        COMPUTE_STORE(a0, a1, a2, a3);
        a0 = b0; a1 = b1; a2 = b2; a3 = b3;
    }
    COMPUTE_STORE(a0, a1, a2, a3);

#undef COMPUTE_STORE
#undef FMA4
}

extern "C" void kernel_launch(void* const* d_in, const int* in_sizes, int n_in,
                              void* d_out, int out_size, void* d_ws, size_t ws_size,
                              hipStream_t stream) {
    const float* x1  = (const float*)d_in[0];
    const float* x2  = (const float*)d_in[1];
    const float* lsb = (const float*)d_in[2];
    const float* lsv = (const float*)d_in[3];
    const float* off = (const float*)d_in[4];
    float* out = (float*)d_out;

    const int n = in_sizes[0] / 16;   // 8192
    const int m = in_sizes[1] / 16;   // 8192

    dim3 grid(m / BLOCK_COLS, n / ROWS_PER_BLOCK);   // 8 x 256 = 2048 blocks
    linear_kernel<<<grid, 256, 0, stream>>>(x1, x2, lsb, lsv, off, out, n, m);
}